// Round 1
// 96.779 us; speedup vs baseline: 1.5595x; 1.5595x over previous
//
#include <hip/hip_runtime.h>
#include <math.h>

#define POOLED      7
#define OUTPUT_DIM  21
#define GROUP       7
#define CHANNELS    (OUTPUT_DIM * GROUP * GROUP)   // 1029
#define FH          64
#define FW          64
#define PLANE       (FH * FW)                      // 4096 floats, 16 KB
#define NUM_ROIS    1024
#define SCALE       0.0625f

// Opaque VGPR pin: blocks FMA contraction (hipcc -ffp-contract=fast ignores
// `#pragma clang fp contract(off)`). CORRECTNESS-CRITICAL: the golden's
// boundary chain is f32, separately rounded, with bin = roi * RN(1/7)
// (reciprocal multiply) — verified round 10, absmax 3.9e-3. Do not change.
__device__ __forceinline__ float freeze(float x) {
    __asm__ volatile("" : "+v"(x));
    return x;
}

// BIN-MAJOR + LDS-STAGED (round 12): one block per channel c=(d*7+ph)*7+pw.
// Block stages its exclusive working set (4 batch planes x 16 KB = 64 KB)
// into LDS with coalesced float4 loads -> HBM feature fetch is exactly-once
// and fully coalesced. 1024 threads (16 waves), 1 ROI/thread: 1029x16 =
// 16464 waves; 64 KB LDS => 2 blocks/CU = 32 waves/CU (100% occupancy cap),
// fixing the old 4116-wave grid (<=50% occupancy, latency-bound at 6% VALU).
// The divergent per-ROI region sum reads LDS instead of scattered L2.
//
// TO_WS=true: write ws[c*1024+n] (4 KB contiguous per block, coalesced);
// a tiled transpose kernel then emits out[n*1029+c]. Kills the 11x write
// amplification (47 MB for a 4.2 MB output) + ~38 MB of RMW write-allocate
// fetch that the old stride-4116B scatter store caused.
template<bool TO_WS>
__global__ __launch_bounds__(1024)
void psroi_lds(const float* __restrict__ feat,
               const float* __restrict__ rois,
               float* __restrict__ dst) {
    const int c  = blockIdx.x;            // 0..1028  (== d*49 + ph*7 + pw)
    const int pw = c % 7;
    const int ph = (c / 7) % 7;
    const int t  = threadIdx.x;           // 0..1023 == ROI index

    __shared__ float pl[4 * PLANE];       // 64 KB: 4 batch planes of channel c

    // ROI load + boundary chain first: independent of LDS, overlaps staging.
    const float* r = rois + t * 5;
    const int b = (int)r[0];

    // ---- frozen boundary chain (golden convention, r10-verified) ----
    float start_w = rintf(r[1]) * SCALE;          // np.round = half-even
    float start_h = rintf(r[2]) * SCALE;
    float end_w   = rintf(r[3] + 1.0f) * SCALE;
    float end_h   = rintf(r[4] + 1.0f) * SCALE;

    float roi_w = fmaxf(end_w - start_w, 0.1f);
    float roi_h = fmaxf(end_h - start_h, 0.1f);

    const float inv7 = 1.0f / 7.0f;               // RN(1/7)
    float bin_h = freeze(roi_h * inv7);           // reciprocal multiply
    float bin_w = freeze(roi_w * inv7);

    float mh0 = freeze((float)ph * bin_h);        // separate mul, then add
    float mh1 = freeze((float)(ph + 1) * bin_h);
    float mw0 = freeze((float)pw * bin_w);
    float mw1 = freeze((float)(pw + 1) * bin_w);

    float hs_f = floorf(mh0 + start_h);
    float he_f = ceilf (mh1 + start_h);
    float ws_f = floorf(mw0 + start_w);
    float we_f = ceilf (mw1 + start_w);

    int hs = (int)fminf(fmaxf(hs_f, 0.0f), (float)FH);
    int he = (int)fminf(fmaxf(he_f, 0.0f), (float)FH);
    int ws = (int)fminf(fmaxf(ws_f, 0.0f), (float)FW);
    int we = (int)fminf(fmaxf(we_f, 0.0f), (float)FW);
    // ---- end frozen chain ----

    // Stage 4 batch planes of channel c: 4x 16 KB, one float4 per thread per
    // batch, fully coalesced (1024 lanes x 16 B = one 16 KB plane per iter).
#pragma unroll
    for (int bb = 0; bb < 4; ++bb) {
        const float4* src = reinterpret_cast<const float4*>(
            feat + ((size_t)bb * CHANNELS + c) * PLANE);
        reinterpret_cast<float4*>(pl + bb * PLANE)[t] = src[t];
    }
    __syncthreads();

    const float* base = pl + b * PLANE;
    float s = 0.0f;
    for (int h = hs; h < he; ++h) {
        const float* row = base + h * FW;
        for (int w = ws; w < we; ++w) {
            s += row[w];
        }
    }

    int area = (he - hs) * (we - ws);
    float v = (area <= 0) ? 0.0f : s / (float)area;

    if (TO_WS) {
        dst[(size_t)c * NUM_ROIS + t] = v;        // coalesced, contiguous 4 KB
    } else {
        dst[(size_t)t * CHANNELS + c] = v;        // fallback scatter store
    }
}

// ws[1029][1024] -> out[1024][1029]. 32x32 tiles, 256 threads, 33-pad LDS
// (conflict-free column reads). Reads coalesced along n, writes coalesced
// along c. Traffic: 4.2 MB in + 4.2 MB out.
__global__ __launch_bounds__(256)
void transpose_cn(const float* __restrict__ ws, float* __restrict__ out) {
    __shared__ float tile[32][33];
    const int c0 = blockIdx.y * 32;
    const int n0 = blockIdx.x * 32;
    const int tx = threadIdx.x & 31;
    const int ty = threadIdx.x >> 5;              // 0..7

#pragma unroll
    for (int i = 0; i < 32; i += 8) {
        const int cc = c0 + ty + i;
        if (cc < CHANNELS)
            tile[ty + i][tx] = ws[(size_t)cc * NUM_ROIS + (n0 + tx)];
    }
    __syncthreads();
#pragma unroll
    for (int i = 0; i < 32; i += 8) {
        const int nn = n0 + ty + i;
        const int cc = c0 + tx;
        if (cc < CHANNELS)
            out[(size_t)nn * CHANNELS + cc] = tile[tx][ty + i];
    }
}

extern "C" void kernel_launch(void* const* d_in, const int* in_sizes, int n_in,
                              void* d_out, int out_size, void* d_ws, size_t ws_size,
                              hipStream_t stream) {
    const float* feat = (const float*)d_in[0];
    const float* rois = (const float*)d_in[1];
    float* out = (float*)d_out;

    const size_t need = sizeof(float) * (size_t)CHANNELS * NUM_ROIS;
    if (d_ws != nullptr && ws_size >= need) {
        float* ws = (float*)d_ws;
        psroi_lds<true><<<CHANNELS, 1024, 0, stream>>>(feat, rois, ws);
        transpose_cn<<<dim3(NUM_ROIS / 32, (CHANNELS + 31) / 32), 256, 0, stream>>>(ws, out);
    } else {
        psroi_lds<false><<<CHANNELS, 1024, 0, stream>>>(feat, rois, out);
    }
}